// Round 3
// baseline (280.044 us; speedup 1.0000x reference)
//
#include <hip/hip_runtime.h>

// Squared Euclidean distance matrix: out[n][m] = sq1[n] + sq2[m] - 2*dot(x1[n],x2[m]), clamped >= 0.
// N = M = 8192, K = 64, fp32 in/out. Output 256 MB -> HBM-write-bound floor ~43us.
// Cross term via bf16 MFMA 16x16x32; norms fp32 exact (absmax ~2 << 5.88 budget).
//
// R3 changes vs R2:
//  - SWAPPED-OPERAND MFMA: mfma(bfr, afr, acc) computes the transposed tile, so
//    each lane's 4 acc regs are 4 CONSECUTIVE output columns -> float4 stores
//    (16B/lane, 4x fewer store instructions) and float4 sq2 reads (broadcast).
//  - HW bf16 convert: (__bf16) cast -> v_cvt_pk_bf16_f32 instead of 4-op manual
//    RNE (~256 -> ~64 VALU instrs/thread in staging).

typedef __bf16 bf16x8 __attribute__((ext_vector_type(8)));
typedef float floatx4 __attribute__((ext_vector_type(4)));

#define TILE 128
#define KD 64
#define LDSS 72   // __bf16 per row: 64 data + 8 pad; row = 144 B, 16B-aligned

__global__ void sqeuclid_mfma(const float* __restrict__ x1,
                              const float* __restrict__ x2,
                              float* __restrict__ out,
                              int M) {
    __shared__ __bf16 a_s[TILE][LDSS];   // x1 tile [row][k], bf16
    __shared__ __bf16 b_s[TILE][LDSS];   // x2 tile [row][k], bf16
    __shared__ float sq1_s[TILE];
    __shared__ float sq2_s[TILE];

    const int t = threadIdx.x;                 // 0..255
    const int block_row = blockIdx.y * TILE;
    const int block_col = blockIdx.x * TILE;

    // ---- Stage fp32 -> bf16 into LDS (HW cvt); fp32 row norms on the side.
    // Thread t stages one full row (L1 caches the 256B row across iters).
    {
        const int r = t & 127;
        const float* src = (t < TILE) ? (x1 + (size_t)(block_row + r) * KD)
                                      : (x2 + (size_t)(block_col + r) * KD);
        __bf16* dst = (t < TILE) ? a_s[r] : b_s[r];
        float nrm = 0.f;
        #pragma unroll
        for (int i = 0; i < 8; ++i) {          // 2 float4 -> 1 bf16x8 (16B LDS write)
            const float4 f0 = ((const float4*)src)[2 * i];
            const float4 f1 = ((const float4*)src)[2 * i + 1];
            nrm = fmaf(f0.x, f0.x, nrm); nrm = fmaf(f0.y, f0.y, nrm);
            nrm = fmaf(f0.z, f0.z, nrm); nrm = fmaf(f0.w, f0.w, nrm);
            nrm = fmaf(f1.x, f1.x, nrm); nrm = fmaf(f1.y, f1.y, nrm);
            nrm = fmaf(f1.z, f1.z, nrm); nrm = fmaf(f1.w, f1.w, nrm);
            bf16x8 pk;
            pk[0] = (__bf16)f0.x; pk[1] = (__bf16)f0.y;
            pk[2] = (__bf16)f0.z; pk[3] = (__bf16)f0.w;
            pk[4] = (__bf16)f1.x; pk[5] = (__bf16)f1.y;
            pk[6] = (__bf16)f1.z; pk[7] = (__bf16)f1.w;
            *(bf16x8*)&dst[i * 8] = pk;
        }
        if (t < TILE) sq1_s[r] = nrm; else sq2_s[r] = nrm;
    }
    __syncthreads();

    // ---- MFMA, swapped operands. Fragments: lane holds 8 bf16 along k from
    // row (lane&15) of its tile; identical layout serves as A- or B-operand.
    // mfma(bfr[j], afr[i], .) => D[m][n] = dot(x2[wc+j*16+m], x1[wr+i*16+n])
    // with lane mapping n = lane&15 (x1 row), m = (lane>>4)*4 + reg (x2 col):
    // each lane's 4 regs = 4 consecutive output COLUMNS.
    const int wave = t >> 6, lane = t & 63;
    const int wr = (wave >> 1) * 64;           // quadrant row base (x1)
    const int wc = (wave & 1) * 64;            // quadrant col base (x2)
    const int lm = lane & 15, lq = lane >> 4;

    floatx4 acc[4][4];
    #pragma unroll
    for (int i = 0; i < 4; ++i)
        #pragma unroll
        for (int j = 0; j < 4; ++j)
            acc[i][j] = (floatx4){0.f, 0.f, 0.f, 0.f};

    #pragma unroll
    for (int ks = 0; ks < 2; ++ks) {
        const int koff = ks * 32 + lq * 8;     // 16B-aligned
        bf16x8 afr[4], bfr[4];
        #pragma unroll
        for (int i = 0; i < 4; ++i) {
            afr[i] = *(const bf16x8*)&a_s[wr + i * 16 + lm][koff];
            bfr[i] = *(const bf16x8*)&b_s[wc + i * 16 + lm][koff];
        }
        #pragma unroll
        for (int i = 0; i < 4; ++i)
            #pragma unroll
            for (int j = 0; j < 4; ++j)
                acc[i][j] = __builtin_amdgcn_mfma_f32_16x16x32_bf16(
                    bfr[j], afr[i], acc[i][j], 0, 0, 0);
    }

    // ---- Epilogue: d2 = sq1 + sq2 - 2*dot, clamp, float4 stores.
    #pragma unroll
    for (int i = 0; i < 4; ++i) {
        const int lrow = wr + i * 16 + lm;
        const float s1 = sq1_s[lrow];
        const size_t gbase = (size_t)(block_row + lrow) * M + block_col;
        #pragma unroll
        for (int j = 0; j < 4; ++j) {
            const int lcol = wc + j * 16 + lq * 4;
            const float4 s2 = *(const float4*)&sq2_s[lcol];
            float4 o;
            o.x = fmaxf(fmaf(-2.f, acc[i][j][0], s1 + s2.x), 0.f);
            o.y = fmaxf(fmaf(-2.f, acc[i][j][1], s1 + s2.y), 0.f);
            o.z = fmaxf(fmaf(-2.f, acc[i][j][2], s1 + s2.z), 0.f);
            o.w = fmaxf(fmaf(-2.f, acc[i][j][3], s1 + s2.w), 0.f);
            *(float4*)(out + gbase + lcol) = o;
        }
    }
}

extern "C" void kernel_launch(void* const* d_in, const int* in_sizes, int n_in,
                              void* d_out, int out_size, void* d_ws, size_t ws_size,
                              hipStream_t stream) {
    const float* x1 = (const float*)d_in[0];
    const float* x2 = (const float*)d_in[1];
    float* out = (float*)d_out;
    const int N = in_sizes[0] / KD;   // 8192
    const int M = in_sizes[1] / KD;   // 8192

    dim3 grid(M / TILE, N / TILE);    // (64, 64)
    dim3 block(256);
    sqeuclid_mfma<<<grid, block, 0, stream>>>(x1, x2, out, M);
}